// Round 12
// baseline (448.550 us; speedup 1.0000x reference)
//
#include <hip/hip_runtime.h>
#include <math.h>

// Problem constants (from reference setup_inputs)
constexpr int Bq = 32;
constexpr int Tq = 8192;
constexpr int Dq = 8;
constexpr int Qq = 8;
constexpr int Kq = 1024;
constexpr int NTOK = Bq * Tq;                         // 262144 tokens
constexpr float LOSS_SCALE = 0.25f / (float)(Bq * Tq * Dq);

// ws layout (floats): per-q region of 9216 floats (36864 B):
//   [0 .. 8191]  bf16 frag u32s, SWIZZLED (see R24 note)
//   [8192..9215] cnh = -cn/2 (1024 floats)
// after 8 regions (73728 floats): cnmax[8]
constexpr int WS_QSTRIDE = 9216;                      // floats per q region
constexpr int WS_CNMAX   = 8 * WS_QSTRIDE;            // float offset of cnmax[8]
constexpr size_t WS_NEED_BYTES = (size_t)(WS_CNMAX + 8) * 4;

typedef __attribute__((ext_vector_type(8))) short short8;    // 8 bf16 (4 VGPRs)
typedef __attribute__((ext_vector_type(4))) float f32x4;
typedef __attribute__((ext_vector_type(16))) float f32x16;
typedef __attribute__((ext_vector_type(4))) unsigned int u32x4;

// R24: R23 + bank-conflict swizzle on the frag layout.
// R23 post-mortem: 32x32 layout PASSED (operand/CD mapping validated)
// and VALU work dropped as designed (VALUBusy*dur 244->188us-equiv,
// VGPR 48, occ 41%) -- but dur went 369->422 because
// SQ_LDS_BANK_CONFLICT rose 12x (1.14M->13.6M). The A-frag ds_read_b128
// hits byte (blk*32+tcol)*32 + half*16; 16B-unit u = tcol*2+half. Lanes
// 0..31 all have half=0 -> every 16-lane issue group reads only even
// units -> bank-quads {0,2,4,6} -> half the banks idle, 2x+ systematic
// conflict per hot-loop load.
// Fix (free, both-sides -- guide rule #21): prep STORES frag (cw,half)
// at swizzled unit u' = u ^ ((u>>3)&1) (XOR half with bit2 of cw);
// main READS with the same involution (hsw = (half ^ ((tcol>>2)&1))*4).
// gload_lds stays linear 1:1. Each 16-lane group then covers all 8
// bank-quads exactly twice (tcol 0..7, half 0 -> {0,2,4,6,1,3,5,7}).
// cnh/cinit reads are wave-broadcast (2 addrs) = free, untouched.
// Everything else R23-identical:
// A row cw = lane&31, half = lane>>5 owns K 8h..8h+7, K = [ch|cl];
// B: mfma1=[rh|rl], mfma2=[rl|rh]; acc = mfma(a,b2, mfma(a,b1,cinit)).
// C/D: col=lane&31, row=(r&3)+8*(r>>2)+4*half. 16-cand group-max
// tracking (R17 proof); exact 16-cand fix-up; margin=6e-5*(rn+cnmax);
// flagged -> R13 wave-coop EXACT rescan -> np.argmin semantics.
// launch_bounds(512,4): 4 blocks/CU, VGPR cap 64 (R21/R22-proven).
// Staging: async global_load_lds width=16, 36 x 1KB chunks (R20).

__device__ __forceinline__ void gload_lds16(const void* gsrc, void* ldst) {
    __builtin_amdgcn_global_load_lds(
        (const __attribute__((address_space(1))) unsigned int*)gsrc,
        (__attribute__((address_space(3))) unsigned int*)ldst,
        16, 0, 0);
}

__global__ __launch_bounds__(512)
void rvq_prep(const float* __restrict__ codebooks, float* __restrict__ ws)
{
    __shared__ float s_red[8];
    const int tid  = threadIdx.x;
    const int lane = tid & 63;
    const int wave = tid >> 6;
    const int q    = blockIdx.x;                   // 8 blocks, one per q
    const float* cbq = codebooks + (size_t)q * Kq * Dq;
    float* wq = ws + (size_t)q * WS_QSTRIDE;
    unsigned* frag = reinterpret_cast<unsigned*>(wq);
    float* cnh = wq + Kq * 8;

    float nmax = 0.0f;
#pragma unroll
    for (int it = 0; it < 2; ++it) {
        int n = tid + it * 512;
        const float4* cp = reinterpret_cast<const float4*>(cbq + (size_t)n * 8);
        float4 ca = cp[0], cc = cp[1];
        float c[8] = {ca.x, ca.y, ca.z, ca.w, cc.x, cc.y, cc.z, cc.w};
        float nn = __fmul_rn(c[0], c[0]);
#pragma unroll
        for (int d = 1; d < 8; ++d)
            nn = __fadd_rn(nn, __fmul_rn(c[d], c[d]));
        cnh[n] = -0.5f * nn;                       // exact scale
        nmax = fmaxf(nmax, nn);
        unsigned hb[8], lb[8];
#pragma unroll
        for (int d = 0; d < 8; ++d) {
            union { float f; unsigned u; } v; v.f = c[d];
            hb[d] = (v.u + 0x7FFFu + ((v.u >> 16) & 1u)) >> 16;   // RNE bf16
            union { unsigned u; float f; } h; h.u = hb[d] << 16;
            union { float f; unsigned u; } w; w.f = __fsub_rn(c[d], h.f);
            lb[d] = (w.u + 0x7FFFu + ((w.u >> 16) & 1u)) >> 16;
        }
        u32x4 wh = {hb[0] | (hb[1] << 16), hb[2] | (hb[3] << 16),
                    hb[4] | (hb[5] << 16), hb[6] | (hb[7] << 16)};
        u32x4 wl = {lb[0] | (lb[1] << 16), lb[2] | (lb[3] << 16),
                    lb[4] | (lb[5] << 16), lb[6] | (lb[7] << 16)};
        // swizzled store: block = n>>5, cwin = n&31; unit u = cwin*2+half,
        // stored at u' = u ^ ((u>>3)&1)  (bit3 of u == bit2 of cwin)
        int blkb = (n >> 5) * 64;                  // 16B units per 1KB block
        int cwin = n & 31;
        int sw = (cwin >> 2) & 1;
        reinterpret_cast<u32x4*>(frag)[blkb + cwin * 2 + sw]       = wh;  // half 0
        reinterpret_cast<u32x4*>(frag)[blkb + cwin * 2 + (1 - sw)] = wl;  // half 1
    }
#pragma unroll
    for (int off = 32; off >= 1; off >>= 1)
        nmax = fmaxf(nmax, __shfl_xor(nmax, off, 64));
    if (lane == 0) s_red[wave] = nmax;
    __syncthreads();
    if (tid == 0) {
        float m = s_red[0];
#pragma unroll
        for (int i = 1; i < 8; ++i) m = fmaxf(m, s_red[i]);
        ws[WS_CNMAX + q] = m;
    }
}

__global__ __launch_bounds__(512, 4)
void rvq_main(const float* __restrict__ x,
              const float* __restrict__ codebooks,
              const float* __restrict__ post_scale,
              const float* __restrict__ post_bias,
              const float* __restrict__ conv_w,
              const float* __restrict__ conv_b,
              const float* __restrict__ ws,
              float* __restrict__ out)
{
    __shared__ __align__(16) unsigned s_all[Kq * 8 + Kq];  // 36 KB: frags | cnh
    unsigned* s_frag = s_all;
    float* s_cnh = reinterpret_cast<float*>(s_all + Kq * 8);

    const int tid  = threadIdx.x;                  // 0..511
    const int lane = tid & 63;
    const int wave = tid >> 6;                     // 0..7
    const int half = lane >> 5;                    // 0..1 (k-group)
    const int tcol = lane & 31;                    // token index (C col)
    const int wbase = blockIdx.x * 256 + wave * 32;

    // residual: token wbase + tcol (both halves duplicate)
    float rg[Dq];
    {
        const float4* xp = reinterpret_cast<const float4*>(
            x + (size_t)(wbase + tcol) * Dq);
        float4 a = xp[0], b = xp[1];
        rg[0]=a.x; rg[1]=a.y; rg[2]=a.z; rg[3]=a.w;
        rg[4]=b.x; rg[5]=b.y; rg[6]=b.z; rg[7]=b.w;
    }

    float qso[Dq];
#pragma unroll
    for (int d = 0; d < Dq; ++d) qso[d] = 0.0f;
    float lossacc = 0.0f;

    float* out_quant = out;                               // [B*T*D]
    float* out_loss  = out + (size_t)NTOK * Dq;           // [1]
    float* out_codes = out_loss + 1;                      // [Q*B*T] as float
    const float* ws_cnmax = ws + WS_CNMAX;

    for (int q = 0; q < Qq; ++q) {
        const float* cbq = codebooks + (size_t)q * Kq * Dq;
        const float* wq = ws + (size_t)q * WS_QSTRIDE;

        // ---- stage: async global_load_lds, 36 x 1KB chunks, no VGPRs ----
        {
            const char* src_base = reinterpret_cast<const char*>(wq);
            char* dst_base = reinterpret_cast<char*>(s_all);
            const int l16 = lane * 16;
#pragma unroll
            for (int c = 0; c < 4; ++c) {
                const int off = (wave * 4 + c) * 1024;    // frag chunks 0..31
                gload_lds16(src_base + off + l16, dst_base + off);
            }
            if (wave < 4) {
                const int off = 32768 + wave * 1024;      // cnh chunks 32..35
                gload_lds16(src_base + off + l16, dst_base + off);
            }
        }
        const float cnmax = ws_cnmax[q];
        __syncthreads();   // compiler drains vmcnt(0) before s_barrier

        // ---- per-lane: rn (np order) + B fragments [rh|rl] / [rl|rh] ----
        float rn;
        short8 bfrag1, bfrag2;
        {
            float n = __fmul_rn(rg[0], rg[0]);
#pragma unroll
            for (int d = 1; d < 8; ++d)
                n = __fadd_rn(n, __fmul_rn(rg[d], rg[d]));
            rn = n;
            short8 rh8, rl8;
#pragma unroll
            for (int d = 0; d < 8; ++d) {
                union { float f; unsigned u; } v; v.f = rg[d];
                unsigned hbb = (v.u + 0x7FFFu + ((v.u >> 16) & 1u)) >> 16;
                union { unsigned u; float f; } h; h.u = hbb << 16;
                union { float f; unsigned u; } w; w.f = __fsub_rn(rg[d], h.f);
                unsigned lbb = (w.u + 0x7FFFu + ((w.u >> 16) & 1u)) >> 16;
                rh8[d] = (short)hbb;
                rl8[d] = (short)lbb;
            }
            bfrag1 = half ? rl8 : rh8;     // mfma1: K = [rh | rl]
            bfrag2 = half ? rh8 : rl8;     // mfma2: K = [rl | rh]
        }

        // ---- main loop: 32 blocks x 32 cw; 16-cand group-max tracking ----
        float m1  = -__builtin_inff();
        float m2g = -__builtin_inff();
        int   gblk = 0;
        // swizzled A-frag read: half ^ bit2(tcol) (matches prep store)
        const int hsw = (half ^ ((tcol >> 2) & 1)) * 4;
        const int h4 = half * 4;
#pragma unroll 1
        for (int blk = 0; blk < Kq / 32; ++blk) {
            // A frag: cw = blk*32 + tcol, half selects ch / cl (swizzled)
            int ab = blk * 256 + tcol * 8 + hsw;          // u32 units
            u32x4 wa = *reinterpret_cast<const u32x4*>(s_frag + ab);
            short8 afrag = __builtin_bit_cast(short8, wa);
            // C init: reg r -> row (r&3)+8*(r>>2)+4*half
            const float* cb0 = s_cnh + blk * 32 + h4;
            f32x4 c0 = *reinterpret_cast<const f32x4*>(cb0);
            f32x4 c1 = *reinterpret_cast<const f32x4*>(cb0 + 8);
            f32x4 c2 = *reinterpret_cast<const f32x4*>(cb0 + 16);
            f32x4 c3 = *reinterpret_cast<const f32x4*>(cb0 + 24);
            f32x16 acc = {c0[0], c0[1], c0[2], c0[3],
                          c1[0], c1[1], c1[2], c1[3],
                          c2[0], c2[1], c2[2], c2[3],
                          c3[0], c3[1], c3[2], c3[3]};
            acc = __builtin_amdgcn_mfma_f32_32x32x16_bf16(afrag, bfrag1, acc, 0, 0, 0);
            acc = __builtin_amdgcn_mfma_f32_32x32x16_bf16(afrag, bfrag2, acc, 0, 0, 0);
            // t = max of 16 (tree; compiler fuses to v_max3)
            float t01 = fmaxf(acc[0], acc[1]),   t23 = fmaxf(acc[2], acc[3]);
            float t45 = fmaxf(acc[4], acc[5]),   t67 = fmaxf(acc[6], acc[7]);
            float t89 = fmaxf(acc[8], acc[9]),   tab = fmaxf(acc[10], acc[11]);
            float tcd = fmaxf(acc[12], acc[13]), tef = fmaxf(acc[14], acc[15]);
            float ta = fmaxf(fmaxf(t01, t23), fmaxf(t45, t67));
            float tb = fmaxf(fmaxf(t89, tab), fmaxf(tcd, tef));
            float t = fmaxf(ta, tb);
            bool gt = t > m1;                      // strict: first blk wins
            gblk = gt ? blk : gblk;
            m2g = fmaxf(m2g, fminf(m1, t));        // covers all losing blocks
            m1  = fmaxf(m1, t);
        }

        // ---- fix-up: exact f32 re-eval of winning block's 16 cands ----
        float M1, M2;
        int bk, fl;
        {
            int base = gblk * 32 + h4;
            float best = -__builtin_inff(), sec = -__builtin_inff();
            int bki = base;
#pragma unroll 4
            for (int r = 0; r < 16; ++r) {
                int k = base + (r & 3) + 8 * (r >> 2);    // ascending in r
                const float4* cp = reinterpret_cast<const float4*>(cbq + (size_t)k * 8);
                float4 ca = cp[0], cc = cp[1];
                float dot = __fmul_rn(rg[0], ca.x);       // np-order chain
                dot = fmaf(rg[1], ca.y, dot);
                dot = fmaf(rg[2], ca.z, dot);
                dot = fmaf(rg[3], ca.w, dot);
                dot = fmaf(rg[4], cc.x, dot);
                dot = fmaf(rg[5], cc.y, dot);
                dot = fmaf(rg[6], cc.z, dot);
                dot = fmaf(rg[7], cc.w, dot);
                float Dx = __fadd_rn(dot, s_cnh[k]);      // dot - cn/2, exact
                bool w = Dx > best;                       // strict: lowest k wins
                sec = fmaxf(sec, fminf(best, Dx));
                bki = w ? k : bki;
                best = fmaxf(best, Dx);
            }
            M1 = best;
            M2 = fmaxf(sec, m2g);                         // mixed-domain runner-up
            bk = bki;
        }

        // ---- merge lane pair (xor 32); lex (D desc, k asc); flag ties ----
        {
            float A1 = M1, A2 = M2; int K1 = bk;
            float o1 = __shfl_xor(A1, 32, 64);
            float o2 = __shfl_xor(A2, 32, 64);
            int   ok = __shfl_xor(K1, 32, 64);
            bool ow = (o1 > A1) || (o1 == A1 && ok < K1);
            A2 = ow ? fmaxf(A1, o2) : fmaxf(o1, A2);
            A1 = ow ? o1 : A1; K1 = ow ? ok : K1;
            float margin = (rn + cnmax) * 6e-5f;          // bf16 + mixed-domain err
            fl = (__fsub_rn(A1, A2) <= margin) ? 1 : 0;
            bk = K1;
        }

        // ---- rare: wave-cooperative EXACT rescan (np chain, first-min) ----
        {
            unsigned long long msk = __ballot(fl && (lane < 32));
            while (msk) {
                int p = __builtin_ctzll(msk); msk &= (msk - 1);
                float rt[8];
#pragma unroll
                for (int d = 0; d < 8; ++d) rt[d] = __shfl(rg[d], p, 64);
                float rnt = __shfl(rn, p, 64);
                float bb = __builtin_inff(); int bkk = 0;
#pragma unroll 2
                for (int i = 0; i < 16; ++i) {
                    int k = lane + 64 * i;
                    const float4* cp = reinterpret_cast<const float4*>(cbq + (size_t)k * 8);
                    float4 ca = cp[0], cc = cp[1];
                    float c8[8] = {ca.x, ca.y, ca.z, ca.w, cc.x, cc.y, cc.z, cc.w};
                    float cn = __fmul_rn(c8[0], c8[0]);          // np-order cn
#pragma unroll
                    for (int d = 1; d < 8; ++d)
                        cn = __fadd_rn(cn, __fmul_rn(c8[d], c8[d]));
                    float dot = __fmul_rn(rt[0], c8[0]);
                    dot = fmaf(rt[1], c8[1], dot);
                    dot = fmaf(rt[2], c8[2], dot);
                    dot = fmaf(rt[3], c8[3], dot);
                    dot = fmaf(rt[4], c8[4], dot);
                    dot = fmaf(rt[5], c8[5], dot);
                    dot = fmaf(rt[6], c8[6], dot);
                    dot = fmaf(rt[7], c8[7], dot);
                    float d2 = fmaf(dot, -2.0f, __fadd_rn(rnt, cn));
                    if (d2 < bb) { bb = d2; bkk = k; }           // k asc in-lane
                }
#pragma unroll
                for (int mm = 1; mm <= 32; mm <<= 1) {
                    float ob = __shfl_xor(bb, mm, 64);
                    int   ok = __shfl_xor(bkk, mm, 64);
                    if (ob < bb || (ob == bb && ok < bkk)) { bb = ob; bkk = ok; }
                }
                if (tcol == p) bk = bkk;               // both halves of token p
            }
        }

        // ---- codes + exact update (np chains; embed from L2-hot global) ----
        const float sc = post_scale[q];
        const float bi = post_bias[q];
        if (half == 0)
            out_codes[(size_t)q * NTOK + wbase + tcol] = (float)bk;
        {
            const float4* ep = reinterpret_cast<const float4*>(cbq + (size_t)bk * 8);
            float4 ea = ep[0], eb = ep[1];
            float e[8] = {ea.x, ea.y, ea.z, ea.w, eb.x, eb.y, eb.z, eb.w};
#pragma unroll
            for (int d = 0; d < 8; ++d) {
                float rd = rg[d];
                float est = __fadd_rn(rd, __fsub_rn(e[d], rd));
                if (half == 0) {
                    qso[d] = __fadd_rn(__fadd_rn(qso[d], __fmul_rn(est, sc)), bi);
                }
                float nr = __fsub_rn(rd, e[d]);
                float df = __fsub_rn(nr, e[d]);
                if (half == 0) lossacc = fmaf(df, df, lossacc);
                rg[d] = nr;
            }
        }
        __syncthreads();   // s_all reads done before next q's copy
    }

    // ---- 1x1 conv epilogue: owner lanes (half 0) write their token ----
    if (half == 0) {
        float o[8];
#pragma unroll
        for (int e2 = 0; e2 < 8; ++e2) {
            float acc = __fmul_rn(qso[0], conv_w[e2 * 8 + 0]);
#pragma unroll
            for (int d = 1; d < 8; ++d)
                acc = fmaf(qso[d], conv_w[e2 * 8 + d], acc);
            o[e2] = __fadd_rn(acc, conv_b[e2]);
        }
        float4* op = reinterpret_cast<float4*>(
            out_quant + (size_t)(wbase + tcol) * Dq);
        op[0] = make_float4(o[0], o[1], o[2], o[3]);
        op[1] = make_float4(o[4], o[5], o[6], o[7]);
    }

    // ---- loss reduction (owner lanes contributed; rest are 0) ----
    float v = lossacc;
#pragma unroll
    for (int off = 32; off >= 1; off >>= 1)
        v += __shfl_xor(v, off, 64);
    if (lane == 0)
        atomicAdd(out_loss, v * LOSS_SCALE);
}

// ---- R17-style fallback (proven) if workspace is too small ----
__global__ __launch_bounds__(512, 2)
void rvq_mono(const float* __restrict__ x,
              const float* __restrict__ codebooks,
              const float* __restrict__ post_scale,
              const float* __restrict__ post_bias,
              const float* __restrict__ conv_w,
              const float* __restrict__ conv_b,
              float* __restrict__ out)
{
    __shared__ __align__(16) unsigned s_frag[Kq * 8];
    __shared__ __align__(16) float s_cnh[Kq];
    __shared__ float s_red[8];

    const int tid  = threadIdx.x;
    const int lane = tid & 63;
    const int wave = tid >> 6;
    const int quad = lane >> 4;
    const int col  = lane & 15;
    const int wbase = blockIdx.x * 256 + wave * 32;

    float rg[2][Dq];
#pragma unroll
    for (int g = 0; g < 2; ++g) {
        const float4* xp = reinterpret_cast<const float4*>(
            x + (size_t)(wbase + g * 16 + col) * Dq);
        float4 a = xp[0], b = xp[1];
        rg[g][0]=a.x; rg[g][1]=a.y; rg[g][2]=a.z; rg[g][3]=a.w;
        rg[g][4]=b.x; rg[g][5]=b.y; rg[g][6]=b.z; rg[g][7]=b.w;
    }

    float qso[Dq];
#pragma unroll
    for (int d = 0; d < Dq; ++d) qso[d] = 0.0f;
    float lossacc = 0.0f;

    float* out_quant = out;
    float* out_loss  = out + (size_t)NTOK * Dq;
    float* out_codes = out_loss + 1;

    for (int q = 0; q < Qq; ++q) {
        const float* cbq = codebooks + (size_t)q * Kq * Dq;

        float nmax = 0.0f;
#pragma unroll
        for (int it = 0; it < 2; ++it) {
            int n = tid + it * 512;
            const float4* cp = reinterpret_cast<const float4*>(cbq + (size_t)n * 8);
            float4 ca = cp[0], cc = cp[1];
            float c[8] = {ca.x, ca.y, ca.z, ca.w, cc.x, cc.y, cc.z, cc.w};
            float nn = __fmul_rn(c[0], c[0]);
#pragma unroll
            for (int d = 1; d < 8; ++d)
                nn = __fadd_rn(nn, __fmul_rn(c[d], c[d]));
            s_cnh[n] = -0.5f * nn;
            nmax = fmaxf(nmax, nn);
            unsigned hb[8], lb[8];
#pragma unroll
            for (int d = 0; d < 8; ++d) {
                union { float f; unsigned u; } v; v.f = c[d];
                hb[d] = (v.u + 0x7FFFu + ((v.u >> 16) & 1u)) >> 16;
                union { unsigned u; float f; } h; h.u = hb[d] << 16;
                union { float f; unsigned u; } w; w.f = __fsub_rn(c[d], h.f);
                lb[d] = (w.u + 0x7FFFu + ((w.u >> 16) & 1u)) >> 16;
            }
            u32x4 wh = {hb[0] | (hb[1] << 16), hb[2] | (hb[3] << 16),
                        hb[4] | (hb[5] << 16), hb[6] | (hb[7] << 16)};
            u32x4 wl = {lb[0] | (lb[1] << 16), lb[2] | (lb[3] << 16),
                        lb[4] | (lb[5] << 16), lb[6] | (lb[7] << 16)};
            reinterpret_cast<u32x4*>(s_frag)[n * 2]     = wh;
            reinterpret_cast<u32x4*>(s_frag)[n * 2 + 1] = wl;
        }
#pragma unroll
        for (int off = 32; off >= 1; off >>= 1)
            nmax = fmaxf(nmax, __shfl_xor(nmax, off, 64));
        if (lane == 0) s_red[wave] = nmax;
        __syncthreads();
        float cnmax = s_red[0];
#pragma unroll
        for (int i = 1; i < 8; ++i) cnmax = fmaxf(cnmax, s_red[i]);

        float rn_own[2];
        short8 bfrag[2];
#pragma unroll
        for (int g = 0; g < 2; ++g) {
            float n = __fmul_rn(rg[g][0], rg[g][0]);
#pragma unroll
            for (int d = 1; d < 8; ++d)
                n = __fadd_rn(n, __fmul_rn(rg[g][d], rg[g][d]));
            rn_own[g] = n;
            short8 bf;
#pragma unroll
            for (int d = 0; d < 8; ++d) {
                union { float f; unsigned u; } v; v.f = rg[g][d];
                unsigned hbb = (v.u + 0x7FFFu + ((v.u >> 16) & 1u)) >> 16;
                union { unsigned u; float f; } h; h.u = hbb << 16;
                union { float f; unsigned u; } w; w.f = __fsub_rn(rg[g][d], h.f);
                unsigned lbb = (w.u + 0x7FFFu + ((w.u >> 16) & 1u)) >> 16;
                bf[d] = (short)((quad >> 1) ? lbb : hbb);
            }
            bfrag[g] = bf;
        }

        float m1[2]  = {-__builtin_inff(), -__builtin_inff()};
        float m2g[2] = {-__builtin_inff(), -__builtin_inff()};
        int   gtile[2] = {0, 0};
        const int fsel = (quad & 1) * 4;
        const int quad4 = quad * 4;
#pragma unroll 2
        for (int tile = 0; tile < Kq / 16; ++tile) {
            f32x4 cinit = *reinterpret_cast<const f32x4*>(s_cnh + tile * 16 + quad4);
            int fb = (tile * 16 + col) * 8 + fsel;
            uint2 w0 = *reinterpret_cast<const uint2*>(s_frag + fb);
            uint2 w1 = *reinterpret_cast<const uint2*>(s_frag + fb + 2);
            u32x4 wa = {w0.x, w0.y, w1.x, w1.y};
            short8 afrag = __builtin_bit_cast(short8, wa);
#pragma unroll
            for (int g = 0; g < 2; ++g) {
                f32x4 acc = __builtin_amdgcn_mfma_f32_16x16x32_bf16(afrag, bfrag[g], cinit, 0, 0, 0);
                float t = fmaxf(fmaxf(fmaxf(acc[0], acc[1]), acc[2]), acc[3]);
                bool gt = t > m1[g];
                gtile[g] = gt ? tile : gtile[g];
                m2g[g] = fmaxf(m2g[g], fminf(m1[g], t));
                m1[g]  = fmaxf(m1[g], t);
            }
        }

        float M1[2], M2[2];
        int bk[2], fl[2];
#pragma unroll
        for (int g = 0; g < 2; ++g) {
            int base = gtile[g] * 16 + quad4;
            float best = -__builtin_inff(), sec = -__builtin_inff();
            int breg = 0;
#pragma unroll
            for (int r = 0; r < 4; ++r) {
                int k = base + r;
                const float4* cp = reinterpret_cast<const float4*>(cbq + (size_t)k * 8);
                float4 ca = cp[0], cc = cp[1];
                float dot = __fmul_rn(rg[g][0], ca.x);
                dot = fmaf(rg[g][1], ca.y, dot);
                dot = fmaf(rg[g][2], ca.z, dot);
                dot = fmaf(rg[g][3], ca.w, dot);
                dot = fmaf(rg[g][4], cc.x, dot);
                dot = fmaf(rg[g][5], cc.y, dot);
                dot = fmaf(rg[g][6], cc.z, dot);
                dot = fmaf(rg[g][7], cc.w, dot);
                float Dx = __fadd_rn(dot, s_cnh[k]);
                bool w = Dx > best;
                sec = fmaxf(sec, fminf(best, Dx));
                breg = w ? r : breg;
                best = fmaxf(best, Dx);
            }
            M1[g] = best;
            M2[g] = fmaxf(sec, m2g[g]);
            bk[g] = base + breg;
        }

#pragma unroll
        for (int g = 0; g < 2; ++g) {
            float A1 = M1[g], A2 = M2[g]; int K1 = bk[g];
#pragma unroll
            for (int m = 16; m <= 32; m <<= 1) {
                float o1 = __shfl_xor(A1, m, 64);
                float o2 = __shfl_xor(A2, m, 64);
                int   ok = __shfl_xor(K1, m, 64);
                bool ow = (o1 > A1) || (o1 == A1 && ok < K1);
                A2 = ow ? fmaxf(A1, o2) : fmaxf(o1, A2);
                A1 = ow ? o1 : A1; K1 = ow ? ok : K1;
            }
            float margin = (rn_own[g] + cnmax) * 6e-5f;
            fl[g] = (__fsub_rn(A1, A2) <= margin) ? 1 : 0;
            bk[g] = K1;
        }

#pragma unroll
        for (int g = 0; g < 2; ++g) {
            unsigned long long msk = __ballot(fl[g] && (quad == g));
            while (msk) {
                int p = __builtin_ctzll(msk); msk &= (msk - 1);
                float rt[8];
#pragma unroll
                for (int d = 0; d < 8; ++d) rt[d] = __shfl(rg[g][d], p, 64);
                float rnt = __shfl(rn_own[g], p, 64);
                float bb = __builtin_inff(); int bkk = 0;
#pragma unroll 2
                for (int i = 0; i < 16; ++i) {
                    int k = lane + 64 * i;
                    const float4* cp = reinterpret_cast<const float4*>(cbq + (size_t)k * 8);
                    float4 ca = cp[0], cc = cp[1];
                    float c8[8] = {ca.x, ca.y, ca.z, ca.w, cc.x, cc.y, cc.z, cc.w};
                    float cn = __fmul_rn(c8[0], c8[0]);
#pragma unroll
                    for (int d = 1; d < 8; ++d)
                        cn = __fadd_rn(cn, __fmul_rn(c8[d], c8[d]));
                    float dot = __fmul_rn(rt[0], c8[0]);
                    dot = fmaf(rt[1], c8[1], dot);
                    dot = fmaf(rt[2], c8[2], dot);
                    dot = fmaf(rt[3], c8[3], dot);
                    dot = fmaf(rt[4], c8[4], dot);
                    dot = fmaf(rt[5], c8[5], dot);
                    dot = fmaf(rt[6], c8[6], dot);
                    dot = fmaf(rt[7], c8[7], dot);
                    float d2 = fmaf(dot, -2.0f, __fadd_rn(rnt, cn));
                    if (d2 < bb) { bb = d2; bkk = k; }
                }
#pragma unroll
                for (int mm = 1; mm <= 32; mm <<= 1) {
                    float ob = __shfl_xor(bb, mm, 64);
                    int   ok = __shfl_xor(bkk, mm, 64);
                    if (ob < bb || (ob == bb && ok < bkk)) { bb = ob; bkk = ok; }
                }
                if (col == (p & 15)) bk[g] = bkk;
            }
        }

        const float sc = post_scale[q];
        const float bi = post_bias[q];
#pragma unroll
        for (int g = 0; g < 2; ++g) {
            if (quad == g)
                out_codes[(size_t)q * NTOK + wbase + g * 16 + col] = (float)bk[g];
            const float4* ep = reinterpret_cast<const float4*>(cbq + (size_t)bk[g] * 8);
            float4 ea = ep[0], eb = ep[1];
            float e[8] = {ea.x, ea.y, ea.z, ea.w, eb.x, eb.y, eb.z, eb.w};
#pragma unroll
            for (int d = 0; d < 8; ++d) {
                float rd = rg[g][d];
                float est = __fadd_rn(rd, __fsub_rn(e[d], rd));
                if (quad == g) {
                    qso[d] = __fadd_rn(__fadd_rn(qso[d], __fmul_rn(est, sc)), bi);
                }
                float nr = __fsub_rn(rd, e[d]);
                float df = __fsub_rn(nr, e[d]);
                if (quad == g) lossacc = fmaf(df, df, lossacc);
                rg[g][d] = nr;
            }
        }
        __syncthreads();
    }

    if (quad < 2) {
        float o[8];
#pragma unroll
        for (int e2 = 0; e2 < 8; ++e2) {
            float acc = __fmul_rn(qso[0], conv_w[e2 * 8 + 0]);
#pragma unroll
            for (int d = 1; d < 8; ++d)
                acc = fmaf(qso[d], conv_w[e2 * 8 + d], acc);
            o[e2] = __fadd_rn(acc, conv_b[e2]);
        }
        float4* op = reinterpret_cast<float4*>(
            out_quant + (size_t)(wbase + quad * 16 + col) * Dq);
        op[0] = make_float4(o[0], o[1], o[2], o[3]);
        op[1] = make_float4(o[4], o[5], o[6], o[7]);
    }

    float v = lossacc;
#pragma unroll
    for (int off = 32; off >= 1; off >>= 1)
        v += __shfl_xor(v, off, 64);
    if (lane == 0)
        atomicAdd(out_loss, v * LOSS_SCALE);
}

extern "C" void kernel_launch(void* const* d_in, const int* in_sizes, int n_in,
                              void* d_out, int out_size, void* d_ws, size_t ws_size,
                              hipStream_t stream) {
    const float* x     = (const float*)d_in[0];
    const float* cb    = (const float*)d_in[1];
    const float* ps    = (const float*)d_in[2];
    const float* pb    = (const float*)d_in[3];
    const float* cw    = (const float*)d_in[4];
    const float* cbias = (const float*)d_in[5];
    float* out = (float*)d_out;

    // zero the loss accumulator slot (d_out is poisoned before every call)
    hipMemsetAsync(out + (size_t)NTOK * Dq, 0, sizeof(float), stream);

    if (d_ws != nullptr && ws_size >= WS_NEED_BYTES) {
        float* ws = (float*)d_ws;
        rvq_prep<<<dim3(Qq), dim3(512), 0, stream>>>(cb, ws);
        rvq_main<<<dim3(NTOK / 256), dim3(512), 0, stream>>>(
            x, cb, ps, pb, cw, cbias, ws, out);
    } else {
        rvq_mono<<<dim3(NTOK / 256), dim3(512), 0, stream>>>(
            x, cb, ps, pb, cw, cbias, out);
    }
}

// Round 13
// 390.810 us; speedup vs baseline: 1.1477x; 1.1477x over previous
//
#include <hip/hip_runtime.h>
#include <math.h>

// Problem constants (from reference setup_inputs)
constexpr int Bq = 32;
constexpr int Tq = 8192;
constexpr int Dq = 8;
constexpr int Qq = 8;
constexpr int Kq = 1024;
constexpr int NTOK = Bq * Tq;                         // 262144 tokens
constexpr float LOSS_SCALE = 0.25f / (float)(Bq * Tq * Dq);

// ws layout (floats): per-q region of 9216 floats (36864 B):
//   [0 .. 8191]  bf16 frag u32s (cw n -> u32x4 ch at n*2, cl at n*2+1)
//   [8192..9215] cnh = -cn/2 (1024 floats)
// after 8 regions (73728 floats): cnmax[8]
constexpr int WS_QSTRIDE = 9216;                      // floats per q region
constexpr int WS_CNMAX   = 8 * WS_QSTRIDE;            // float offset of cnmax[8]
constexpr size_t WS_NEED_BYTES = (size_t)(WS_CNMAX + 8) * 4;

typedef __attribute__((ext_vector_type(8))) short short8;   // 8 bf16 (4 VGPRs)
typedef __attribute__((ext_vector_type(4))) float f32x4;
typedef __attribute__((ext_vector_type(4))) unsigned int u32x4;

// R25: RESTORE R22 verbatim (369us champion). The 32x32 arc (R23/R24,
// ~430-448us twice) is ABANDONED: post-mortem showed its fix-up is 4x
// heavier (32 scattered global loads/lane/q), its s_cnh fix-up reads are
// a 32-way bank conflict (13.6M cycles, identical R23<->R24 -> my A-frag
// swizzle targeted the wrong reads; A-frag was already conflict-free via
// disjoint even/odd bank-quads per half), and the whole kernel ran
// serialized (VALUBusy 43%, MfmaUtil 14%, occ 41% -- all idle).
// R22 structure (all pieces individually proven):
// - 16x16x32 MFMA, full Dekker in ONE mfma: A(cw) k-groups ch,cl,ch,cl
//   (sel quad&1); B(tok) rh,rh,rl,rl (sel quad>>1); K=32 sums all 4
//   cross terms. acc init = -cn/2 (argmin d2 == argmax D).
// - 4-cand group-max tracking (R17 proof): t=max4(acc);
//   gtile=(t>m1)?tile:gtile; m2g=max(m2g,min(m1_old,t)); m1=max(m1,t).
//   Winning tile's 4 cands re-evaluated EXACTLY once per q (f32
//   np-order fma from L2-hot cbq + s_cnh). margin = 6e-5*(rn+cnmax).
//   Near-tie => flagged => R13-proven wave-coop EXACT rescan (np chain,
//   first-min) -> np.argmin semantics unconditionally.
// - prep/ws hoist (R19): codebook bf16/cnh/cnmax converted once by
//   rvq_prep into d_ws; main stages via async global_load_lds width=16
//   (R20), 36 x 1KB chunks, linear LDS dst.
// - launch_bounds(512,4) (R22): 4 blocks/CU (arg2 = min blocks/CU,
//   CUDA semantics -- R21 decoded), VGPR cap 64, all 1024 blocks
//   co-resident in one round. Tile loop #pragma unroll 2 (R16 lesson).

__device__ __forceinline__ void gload_lds16(const void* gsrc, void* ldst) {
    __builtin_amdgcn_global_load_lds(
        (const __attribute__((address_space(1))) unsigned int*)gsrc,
        (__attribute__((address_space(3))) unsigned int*)ldst,
        16, 0, 0);
}

__global__ __launch_bounds__(512)
void rvq_prep(const float* __restrict__ codebooks, float* __restrict__ ws)
{
    __shared__ float s_red[8];
    const int tid  = threadIdx.x;
    const int lane = tid & 63;
    const int wave = tid >> 6;
    const int q    = blockIdx.x;                   // 8 blocks, one per q
    const float* cbq = codebooks + (size_t)q * Kq * Dq;
    float* wq = ws + (size_t)q * WS_QSTRIDE;
    unsigned* frag = reinterpret_cast<unsigned*>(wq);
    float* cnh = wq + Kq * 8;

    float nmax = 0.0f;
#pragma unroll
    for (int it = 0; it < 2; ++it) {
        int n = tid + it * 512;
        const float4* cp = reinterpret_cast<const float4*>(cbq + (size_t)n * 8);
        float4 ca = cp[0], cc = cp[1];
        float c[8] = {ca.x, ca.y, ca.z, ca.w, cc.x, cc.y, cc.z, cc.w};
        float nn = __fmul_rn(c[0], c[0]);
#pragma unroll
        for (int d = 1; d < 8; ++d)
            nn = __fadd_rn(nn, __fmul_rn(c[d], c[d]));
        cnh[n] = -0.5f * nn;                       // exact scale
        nmax = fmaxf(nmax, nn);
        unsigned hb[8], lb[8];
#pragma unroll
        for (int d = 0; d < 8; ++d) {
            union { float f; unsigned u; } v; v.f = c[d];
            hb[d] = (v.u + 0x7FFFu + ((v.u >> 16) & 1u)) >> 16;   // RNE bf16
            union { unsigned u; float f; } h; h.u = hb[d] << 16;
            union { float f; unsigned u; } w; w.f = __fsub_rn(c[d], h.f);
            lb[d] = (w.u + 0x7FFFu + ((w.u >> 16) & 1u)) >> 16;
        }
        u32x4 wh = {hb[0] | (hb[1] << 16), hb[2] | (hb[3] << 16),
                    hb[4] | (hb[5] << 16), hb[6] | (hb[7] << 16)};
        u32x4 wl = {lb[0] | (lb[1] << 16), lb[2] | (lb[3] << 16),
                    lb[4] | (lb[5] << 16), lb[6] | (lb[7] << 16)};
        reinterpret_cast<u32x4*>(frag)[n * 2]     = wh;   // ch
        reinterpret_cast<u32x4*>(frag)[n * 2 + 1] = wl;   // cl
    }
#pragma unroll
    for (int off = 32; off >= 1; off >>= 1)
        nmax = fmaxf(nmax, __shfl_xor(nmax, off, 64));
    if (lane == 0) s_red[wave] = nmax;
    __syncthreads();
    if (tid == 0) {
        float m = s_red[0];
#pragma unroll
        for (int i = 1; i < 8; ++i) m = fmaxf(m, s_red[i]);
        ws[WS_CNMAX + q] = m;
    }
}

__global__ __launch_bounds__(512, 4)
void rvq_main(const float* __restrict__ x,
              const float* __restrict__ codebooks,
              const float* __restrict__ post_scale,
              const float* __restrict__ post_bias,
              const float* __restrict__ conv_w,
              const float* __restrict__ conv_b,
              const float* __restrict__ ws,
              float* __restrict__ out)
{
    __shared__ __align__(16) unsigned s_all[Kq * 8 + Kq];  // 36 KB: frags | cnh
    unsigned* s_frag = s_all;
    float* s_cnh = reinterpret_cast<float*>(s_all + Kq * 8);

    const int tid  = threadIdx.x;                  // 0..511
    const int lane = tid & 63;
    const int wave = tid >> 6;                     // 0..7
    const int quad = lane >> 4;                    // 0..3 (k-group)
    const int col  = lane & 15;                    // token index (C col)
    const int wbase = blockIdx.x * 256 + wave * 32;

    // residuals: token wbase + g*16 + col, g=0,1 (all 4 quads duplicate)
    float rg[2][Dq];
#pragma unroll
    for (int g = 0; g < 2; ++g) {
        const float4* xp = reinterpret_cast<const float4*>(
            x + (size_t)(wbase + g * 16 + col) * Dq);
        float4 a = xp[0], b = xp[1];
        rg[g][0]=a.x; rg[g][1]=a.y; rg[g][2]=a.z; rg[g][3]=a.w;
        rg[g][4]=b.x; rg[g][5]=b.y; rg[g][6]=b.z; rg[g][7]=b.w;
    }

    // owner: quad<2 owns token wbase + quad*16 + col (g == quad)
    float qso[Dq];
#pragma unroll
    for (int d = 0; d < Dq; ++d) qso[d] = 0.0f;
    float lossacc = 0.0f;

    float* out_quant = out;                               // [B*T*D]
    float* out_loss  = out + (size_t)NTOK * Dq;           // [1]
    float* out_codes = out_loss + 1;                      // [Q*B*T] as float
    const float* ws_cnmax = ws + WS_CNMAX;

    for (int q = 0; q < Qq; ++q) {
        const float* cbq = codebooks + (size_t)q * Kq * Dq;
        const float* wq = ws + (size_t)q * WS_QSTRIDE;

        // ---- stage: async global_load_lds, 36 x 1KB chunks, no VGPRs ----
        {
            const char* src_base = reinterpret_cast<const char*>(wq);
            char* dst_base = reinterpret_cast<char*>(s_all);
            const int l16 = lane * 16;
#pragma unroll
            for (int c = 0; c < 4; ++c) {
                const int off = (wave * 4 + c) * 1024;    // frag chunks 0..31
                gload_lds16(src_base + off + l16, dst_base + off);
            }
            if (wave < 4) {
                const int off = 32768 + wave * 1024;      // cnh chunks 32..35
                gload_lds16(src_base + off + l16, dst_base + off);
            }
        }
        const float cnmax = ws_cnmax[q];
        __syncthreads();   // compiler drains vmcnt(0) before s_barrier

        // ---- per-lane: rn (np order) + token B-fragments (rh,rh,rl,rl) ----
        float rn_own[2];
        short8 bfrag[2];
#pragma unroll
        for (int g = 0; g < 2; ++g) {
            float n = __fmul_rn(rg[g][0], rg[g][0]);
#pragma unroll
            for (int d = 1; d < 8; ++d)
                n = __fadd_rn(n, __fmul_rn(rg[g][d], rg[g][d]));
            rn_own[g] = n;
            short8 bf;
#pragma unroll
            for (int d = 0; d < 8; ++d) {
                union { float f; unsigned u; } v; v.f = rg[g][d];
                unsigned hbb = (v.u + 0x7FFFu + ((v.u >> 16) & 1u)) >> 16;
                union { unsigned u; float f; } h; h.u = hbb << 16;
                union { float f; unsigned u; } w; w.f = __fsub_rn(rg[g][d], h.f);
                unsigned lbb = (w.u + 0x7FFFu + ((w.u >> 16) & 1u)) >> 16;
                bf[d] = (short)((quad >> 1) ? lbb : hbb);  // q0,q1=rh; q2,q3=rl
            }
            bfrag[g] = bf;
        }

        // ---- main loop: 64 tiles x 16 cw; per-GROUP max tracking (R17) ----
        float m1[2]  = {-__builtin_inff(), -__builtin_inff()};
        float m2g[2] = {-__builtin_inff(), -__builtin_inff()};
        int   gtile[2] = {0, 0};
        const int fsel = (quad & 1) * 4;               // A half: ch / cl
        const int quad4 = quad * 4;
#pragma unroll 2
        for (int tile = 0; tile < Kq / 16; ++tile) {
            f32x4 cinit = *reinterpret_cast<const f32x4*>(s_cnh + tile * 16 + quad4);
            int fb = (tile * 16 + col) * 8 + fsel;     // u32 units
            uint2 w0 = *reinterpret_cast<const uint2*>(s_frag + fb);
            uint2 w1 = *reinterpret_cast<const uint2*>(s_frag + fb + 2);
            u32x4 wa = {w0.x, w0.y, w1.x, w1.y};
            short8 afrag = __builtin_bit_cast(short8, wa);
#pragma unroll
            for (int g = 0; g < 2; ++g) {
                f32x4 acc = __builtin_amdgcn_mfma_f32_16x16x32_bf16(afrag, bfrag[g], cinit, 0, 0, 0);
                // t = max of 4 (max3+max); strict > keeps FIRST (lowest tile)
                float t = fmaxf(fmaxf(fmaxf(acc[0], acc[1]), acc[2]), acc[3]);
                bool gt = t > m1[g];
                gtile[g] = gt ? tile : gtile[g];
                m2g[g] = fmaxf(m2g[g], fminf(m1[g], t));   // covers all losers
                m1[g]  = fmaxf(m1[g], t);
            }
        }

        // ---- fix-up: exact f32 re-eval of winning group (4 cands) per g ----
        float M1[2], M2[2];
        int bk[2], fl[2];
#pragma unroll
        for (int g = 0; g < 2; ++g) {
            int base = gtile[g] * 16 + quad4;
            float best = -__builtin_inff(), sec = -__builtin_inff();
            int breg = 0;
#pragma unroll
            for (int r = 0; r < 4; ++r) {
                int k = base + r;
                const float4* cp = reinterpret_cast<const float4*>(cbq + (size_t)k * 8);
                float4 ca = cp[0], cc = cp[1];
                float dot = __fmul_rn(rg[g][0], ca.x);      // np-order chain
                dot = fmaf(rg[g][1], ca.y, dot);
                dot = fmaf(rg[g][2], ca.z, dot);
                dot = fmaf(rg[g][3], ca.w, dot);
                dot = fmaf(rg[g][4], cc.x, dot);
                dot = fmaf(rg[g][5], cc.y, dot);
                dot = fmaf(rg[g][6], cc.z, dot);
                dot = fmaf(rg[g][7], cc.w, dot);
                float Dx = __fadd_rn(dot, s_cnh[k]);        // dot - cn/2, exact-domain
                bool w = Dx > best;                         // strict: lowest r wins ties
                sec = fmaxf(sec, fminf(best, Dx));
                breg = w ? r : breg;
                best = fmaxf(best, Dx);
            }
            M1[g] = best;
            M2[g] = fmaxf(sec, m2g[g]);                     // mixed-domain runner-up
            bk[g] = base + breg;
        }

        // ---- merge 4 quads per token col (lex: D desc, k asc); flag ties ----
#pragma unroll
        for (int g = 0; g < 2; ++g) {
            float A1 = M1[g], A2 = M2[g]; int K1 = bk[g];
#pragma unroll
            for (int m = 16; m <= 32; m <<= 1) {
                float o1 = __shfl_xor(A1, m, 64);
                float o2 = __shfl_xor(A2, m, 64);
                int   ok = __shfl_xor(K1, m, 64);
                bool ow = (o1 > A1) || (o1 == A1 && ok < K1);
                A2 = ow ? fmaxf(A1, o2) : fmaxf(o1, A2);
                A1 = ow ? o1 : A1; K1 = ow ? ok : K1;
            }
            float margin = (rn_own[g] + cnmax) * 6e-5f;   // bf16 + mixed-domain err
            fl[g] = (__fsub_rn(A1, A2) <= margin) ? 1 : 0;
            bk[g] = K1;
        }

        // ---- rare: wave-cooperative EXACT rescan (np chain, first-min) ----
#pragma unroll
        for (int g = 0; g < 2; ++g) {
            unsigned long long msk = __ballot(fl[g] && (quad == g));
            while (msk) {
                int p = __builtin_ctzll(msk); msk &= (msk - 1);
                float rt[8];
#pragma unroll
                for (int d = 0; d < 8; ++d) rt[d] = __shfl(rg[g][d], p, 64);
                float rnt = __shfl(rn_own[g], p, 64);
                float bb = __builtin_inff(); int bkk = 0;
#pragma unroll 2
                for (int i = 0; i < 16; ++i) {
                    int k = lane + 64 * i;
                    const float4* cp = reinterpret_cast<const float4*>(cbq + (size_t)k * 8);
                    float4 ca = cp[0], cc = cp[1];
                    float c8[8] = {ca.x, ca.y, ca.z, ca.w, cc.x, cc.y, cc.z, cc.w};
                    float cn = __fmul_rn(c8[0], c8[0]);          // np-order cn
#pragma unroll
                    for (int d = 1; d < 8; ++d)
                        cn = __fadd_rn(cn, __fmul_rn(c8[d], c8[d]));
                    float dot = __fmul_rn(rt[0], c8[0]);
                    dot = fmaf(rt[1], c8[1], dot);
                    dot = fmaf(rt[2], c8[2], dot);
                    dot = fmaf(rt[3], c8[3], dot);
                    dot = fmaf(rt[4], c8[4], dot);
                    dot = fmaf(rt[5], c8[5], dot);
                    dot = fmaf(rt[6], c8[6], dot);
                    dot = fmaf(rt[7], c8[7], dot);
                    float d2 = fmaf(dot, -2.0f, __fadd_rn(rnt, cn));
                    if (d2 < bb) { bb = d2; bkk = k; }           // k asc in-lane
                }
#pragma unroll
                for (int mm = 1; mm <= 32; mm <<= 1) {
                    float ob = __shfl_xor(bb, mm, 64);
                    int   ok = __shfl_xor(bkk, mm, 64);
                    if (ob < bb || (ob == bb && ok < bkk)) { bb = ob; bkk = ok; }
                }
                if (col == (p & 15)) bk[g] = bkk;      // all quads of token p
            }
        }

        // ---- codes + exact update (np chains; embed from L2-hot global) ----
        const float sc = post_scale[q];
        const float bi = post_bias[q];
#pragma unroll
        for (int g = 0; g < 2; ++g) {
            if (quad == g)
                out_codes[(size_t)q * NTOK + wbase + g * 16 + col] = (float)bk[g];
            const float4* ep = reinterpret_cast<const float4*>(cbq + (size_t)bk[g] * 8);
            float4 ea = ep[0], eb = ep[1];
            float e[8] = {ea.x, ea.y, ea.z, ea.w, eb.x, eb.y, eb.z, eb.w};
#pragma unroll
            for (int d = 0; d < 8; ++d) {
                float rd = rg[g][d];
                float est = __fadd_rn(rd, __fsub_rn(e[d], rd));
                if (quad == g) {
                    qso[d] = __fadd_rn(__fadd_rn(qso[d], __fmul_rn(est, sc)), bi);
                }
                float nr = __fsub_rn(rd, e[d]);
                float df = __fsub_rn(nr, e[d]);
                if (quad == g) lossacc = fmaf(df, df, lossacc);
                rg[g][d] = nr;
            }
        }
        __syncthreads();   // s_all reads done before next q's copy
    }

    // ---- 1x1 conv epilogue: owner lanes (quad<2) write their token ----
    if (quad < 2) {
        float o[8];
#pragma unroll
        for (int e2 = 0; e2 < 8; ++e2) {
            float acc = __fmul_rn(qso[0], conv_w[e2 * 8 + 0]);
#pragma unroll
            for (int d = 1; d < 8; ++d)
                acc = fmaf(qso[d], conv_w[e2 * 8 + d], acc);
            o[e2] = __fadd_rn(acc, conv_b[e2]);
        }
        float4* op = reinterpret_cast<float4*>(
            out_quant + (size_t)(wbase + quad * 16 + col) * Dq);
        op[0] = make_float4(o[0], o[1], o[2], o[3]);
        op[1] = make_float4(o[4], o[5], o[6], o[7]);
    }

    // ---- loss reduction (owner lanes contributed; rest are 0) ----
    float v = lossacc;
#pragma unroll
    for (int off = 32; off >= 1; off >>= 1)
        v += __shfl_xor(v, off, 64);
    if (lane == 0)
        atomicAdd(out_loss, v * LOSS_SCALE);
}

// ---- R17 fallback (proven) if workspace is too small ----
__global__ __launch_bounds__(512, 2)
void rvq_mono(const float* __restrict__ x,
              const float* __restrict__ codebooks,
              const float* __restrict__ post_scale,
              const float* __restrict__ post_bias,
              const float* __restrict__ conv_w,
              const float* __restrict__ conv_b,
              float* __restrict__ out)
{
    __shared__ __align__(16) unsigned s_frag[Kq * 8];
    __shared__ __align__(16) float s_cnh[Kq];
    __shared__ float s_red[8];

    const int tid  = threadIdx.x;
    const int lane = tid & 63;
    const int wave = tid >> 6;
    const int quad = lane >> 4;
    const int col  = lane & 15;
    const int wbase = blockIdx.x * 256 + wave * 32;

    float rg[2][Dq];
#pragma unroll
    for (int g = 0; g < 2; ++g) {
        const float4* xp = reinterpret_cast<const float4*>(
            x + (size_t)(wbase + g * 16 + col) * Dq);
        float4 a = xp[0], b = xp[1];
        rg[g][0]=a.x; rg[g][1]=a.y; rg[g][2]=a.z; rg[g][3]=a.w;
        rg[g][4]=b.x; rg[g][5]=b.y; rg[g][6]=b.z; rg[g][7]=b.w;
    }

    float qso[Dq];
#pragma unroll
    for (int d = 0; d < Dq; ++d) qso[d] = 0.0f;
    float lossacc = 0.0f;

    float* out_quant = out;
    float* out_loss  = out + (size_t)NTOK * Dq;
    float* out_codes = out_loss + 1;

    for (int q = 0; q < Qq; ++q) {
        const float* cbq = codebooks + (size_t)q * Kq * Dq;

        float nmax = 0.0f;
#pragma unroll
        for (int it = 0; it < 2; ++it) {
            int n = tid + it * 512;
            const float4* cp = reinterpret_cast<const float4*>(cbq + (size_t)n * 8);
            float4 ca = cp[0], cc = cp[1];
            float c[8] = {ca.x, ca.y, ca.z, ca.w, cc.x, cc.y, cc.z, cc.w};
            float nn = __fmul_rn(c[0], c[0]);
#pragma unroll
            for (int d = 1; d < 8; ++d)
                nn = __fadd_rn(nn, __fmul_rn(c[d], c[d]));
            s_cnh[n] = -0.5f * nn;
            nmax = fmaxf(nmax, nn);
            unsigned hb[8], lb[8];
#pragma unroll
            for (int d = 0; d < 8; ++d) {
                union { float f; unsigned u; } v; v.f = c[d];
                hb[d] = (v.u + 0x7FFFu + ((v.u >> 16) & 1u)) >> 16;
                union { unsigned u; float f; } h; h.u = hb[d] << 16;
                union { float f; unsigned u; } w; w.f = __fsub_rn(c[d], h.f);
                lb[d] = (w.u + 0x7FFFu + ((w.u >> 16) & 1u)) >> 16;
            }
            u32x4 wh = {hb[0] | (hb[1] << 16), hb[2] | (hb[3] << 16),
                        hb[4] | (hb[5] << 16), hb[6] | (hb[7] << 16)};
            u32x4 wl = {lb[0] | (lb[1] << 16), lb[2] | (lb[3] << 16),
                        lb[4] | (lb[5] << 16), lb[6] | (lb[7] << 16)};
            reinterpret_cast<u32x4*>(s_frag)[n * 2]     = wh;
            reinterpret_cast<u32x4*>(s_frag)[n * 2 + 1] = wl;
        }
#pragma unroll
        for (int off = 32; off >= 1; off >>= 1)
            nmax = fmaxf(nmax, __shfl_xor(nmax, off, 64));
        if (lane == 0) s_red[wave] = nmax;
        __syncthreads();
        float cnmax = s_red[0];
#pragma unroll
        for (int i = 1; i < 8; ++i) cnmax = fmaxf(cnmax, s_red[i]);

        float rn_own[2];
        short8 bfrag[2];
#pragma unroll
        for (int g = 0; g < 2; ++g) {
            float n = __fmul_rn(rg[g][0], rg[g][0]);
#pragma unroll
            for (int d = 1; d < 8; ++d)
                n = __fadd_rn(n, __fmul_rn(rg[g][d], rg[g][d]));
            rn_own[g] = n;
            short8 bf;
#pragma unroll
            for (int d = 0; d < 8; ++d) {
                union { float f; unsigned u; } v; v.f = rg[g][d];
                unsigned hbb = (v.u + 0x7FFFu + ((v.u >> 16) & 1u)) >> 16;
                union { unsigned u; float f; } h; h.u = hbb << 16;
                union { float f; unsigned u; } w; w.f = __fsub_rn(rg[g][d], h.f);
                unsigned lbb = (w.u + 0x7FFFu + ((w.u >> 16) & 1u)) >> 16;
                bf[d] = (short)((quad >> 1) ? lbb : hbb);
            }
            bfrag[g] = bf;
        }

        float m1[2]  = {-__builtin_inff(), -__builtin_inff()};
        float m2g[2] = {-__builtin_inff(), -__builtin_inff()};
        int   gtile[2] = {0, 0};
        const int fsel = (quad & 1) * 4;
        const int quad4 = quad * 4;
#pragma unroll 2
        for (int tile = 0; tile < Kq / 16; ++tile) {
            f32x4 cinit = *reinterpret_cast<const f32x4*>(s_cnh + tile * 16 + quad4);
            int fb = (tile * 16 + col) * 8 + fsel;
            uint2 w0 = *reinterpret_cast<const uint2*>(s_frag + fb);
            uint2 w1 = *reinterpret_cast<const uint2*>(s_frag + fb + 2);
            u32x4 wa = {w0.x, w0.y, w1.x, w1.y};
            short8 afrag = __builtin_bit_cast(short8, wa);
#pragma unroll
            for (int g = 0; g < 2; ++g) {
                f32x4 acc = __builtin_amdgcn_mfma_f32_16x16x32_bf16(afrag, bfrag[g], cinit, 0, 0, 0);
                float t = fmaxf(fmaxf(fmaxf(acc[0], acc[1]), acc[2]), acc[3]);
                bool gt = t > m1[g];
                gtile[g] = gt ? tile : gtile[g];
                m2g[g] = fmaxf(m2g[g], fminf(m1[g], t));
                m1[g]  = fmaxf(m1[g], t);
            }
        }

        float M1[2], M2[2];
        int bk[2], fl[2];
#pragma unroll
        for (int g = 0; g < 2; ++g) {
            int base = gtile[g] * 16 + quad4;
            float best = -__builtin_inff(), sec = -__builtin_inff();
            int breg = 0;
#pragma unroll
            for (int r = 0; r < 4; ++r) {
                int k = base + r;
                const float4* cp = reinterpret_cast<const float4*>(cbq + (size_t)k * 8);
                float4 ca = cp[0], cc = cp[1];
                float dot = __fmul_rn(rg[g][0], ca.x);
                dot = fmaf(rg[g][1], ca.y, dot);
                dot = fmaf(rg[g][2], ca.z, dot);
                dot = fmaf(rg[g][3], ca.w, dot);
                dot = fmaf(rg[g][4], cc.x, dot);
                dot = fmaf(rg[g][5], cc.y, dot);
                dot = fmaf(rg[g][6], cc.z, dot);
                dot = fmaf(rg[g][7], cc.w, dot);
                float Dx = __fadd_rn(dot, s_cnh[k]);
                bool w = Dx > best;
                sec = fmaxf(sec, fminf(best, Dx));
                breg = w ? r : breg;
                best = fmaxf(best, Dx);
            }
            M1[g] = best;
            M2[g] = fmaxf(sec, m2g[g]);
            bk[g] = base + breg;
        }

#pragma unroll
        for (int g = 0; g < 2; ++g) {
            float A1 = M1[g], A2 = M2[g]; int K1 = bk[g];
#pragma unroll
            for (int m = 16; m <= 32; m <<= 1) {
                float o1 = __shfl_xor(A1, m, 64);
                float o2 = __shfl_xor(A2, m, 64);
                int   ok = __shfl_xor(K1, m, 64);
                bool ow = (o1 > A1) || (o1 == A1 && ok < K1);
                A2 = ow ? fmaxf(A1, o2) : fmaxf(o1, A2);
                A1 = ow ? o1 : A1; K1 = ow ? ok : K1;
            }
            float margin = (rn_own[g] + cnmax) * 6e-5f;
            fl[g] = (__fsub_rn(A1, A2) <= margin) ? 1 : 0;
            bk[g] = K1;
        }

#pragma unroll
        for (int g = 0; g < 2; ++g) {
            unsigned long long msk = __ballot(fl[g] && (quad == g));
            while (msk) {
                int p = __builtin_ctzll(msk); msk &= (msk - 1);
                float rt[8];
#pragma unroll
                for (int d = 0; d < 8; ++d) rt[d] = __shfl(rg[g][d], p, 64);
                float rnt = __shfl(rn_own[g], p, 64);
                float bb = __builtin_inff(); int bkk = 0;
#pragma unroll 2
                for (int i = 0; i < 16; ++i) {
                    int k = lane + 64 * i;
                    const float4* cp = reinterpret_cast<const float4*>(cbq + (size_t)k * 8);
                    float4 ca = cp[0], cc = cp[1];
                    float c8[8] = {ca.x, ca.y, ca.z, ca.w, cc.x, cc.y, cc.z, cc.w};
                    float cn = __fmul_rn(c8[0], c8[0]);
#pragma unroll
                    for (int d = 1; d < 8; ++d)
                        cn = __fadd_rn(cn, __fmul_rn(c8[d], c8[d]));
                    float dot = __fmul_rn(rt[0], c8[0]);
                    dot = fmaf(rt[1], c8[1], dot);
                    dot = fmaf(rt[2], c8[2], dot);
                    dot = fmaf(rt[3], c8[3], dot);
                    dot = fmaf(rt[4], c8[4], dot);
                    dot = fmaf(rt[5], c8[5], dot);
                    dot = fmaf(rt[6], c8[6], dot);
                    dot = fmaf(rt[7], c8[7], dot);
                    float d2 = fmaf(dot, -2.0f, __fadd_rn(rnt, cn));
                    if (d2 < bb) { bb = d2; bkk = k; }
                }
#pragma unroll
                for (int mm = 1; mm <= 32; mm <<= 1) {
                    float ob = __shfl_xor(bb, mm, 64);
                    int   ok = __shfl_xor(bkk, mm, 64);
                    if (ob < bb || (ob == bb && ok < bkk)) { bb = ob; bkk = ok; }
                }
                if (col == (p & 15)) bk[g] = bkk;
            }
        }

        const float sc = post_scale[q];
        const float bi = post_bias[q];
#pragma unroll
        for (int g = 0; g < 2; ++g) {
            if (quad == g)
                out_codes[(size_t)q * NTOK + wbase + g * 16 + col] = (float)bk[g];
            const float4* ep = reinterpret_cast<const float4*>(cbq + (size_t)bk[g] * 8);
            float4 ea = ep[0], eb = ep[1];
            float e[8] = {ea.x, ea.y, ea.z, ea.w, eb.x, eb.y, eb.z, eb.w};
#pragma unroll
            for (int d = 0; d < 8; ++d) {
                float rd = rg[g][d];
                float est = __fadd_rn(rd, __fsub_rn(e[d], rd));
                if (quad == g) {
                    qso[d] = __fadd_rn(__fadd_rn(qso[d], __fmul_rn(est, sc)), bi);
                }
                float nr = __fsub_rn(rd, e[d]);
                float df = __fsub_rn(nr, e[d]);
                if (quad == g) lossacc = fmaf(df, df, lossacc);
                rg[g][d] = nr;
            }
        }
        __syncthreads();
    }

    if (quad < 2) {
        float o[8];
#pragma unroll
        for (int e2 = 0; e2 < 8; ++e2) {
            float acc = __fmul_rn(qso[0], conv_w[e2 * 8 + 0]);
#pragma unroll
            for (int d = 1; d < 8; ++d)
                acc = fmaf(qso[d], conv_w[e2 * 8 + d], acc);
            o[e2] = __fadd_rn(acc, conv_b[e2]);
        }
        float4* op = reinterpret_cast<float4*>(
            out_quant + (size_t)(wbase + quad * 16 + col) * Dq);
        op[0] = make_float4(o[0], o[1], o[2], o[3]);
        op[1] = make_float4(o[4], o[5], o[6], o[7]);
    }

    float v = lossacc;
#pragma unroll
    for (int off = 32; off >= 1; off >>= 1)
        v += __shfl_xor(v, off, 64);
    if (lane == 0)
        atomicAdd(out_loss, v * LOSS_SCALE);
}

extern "C" void kernel_launch(void* const* d_in, const int* in_sizes, int n_in,
                              void* d_out, int out_size, void* d_ws, size_t ws_size,
                              hipStream_t stream) {
    const float* x     = (const float*)d_in[0];
    const float* cb    = (const float*)d_in[1];
    const float* ps    = (const float*)d_in[2];
    const float* pb    = (const float*)d_in[3];
    const float* cw    = (const float*)d_in[4];
    const float* cbias = (const float*)d_in[5];
    float* out = (float*)d_out;

    // zero the loss accumulator slot (d_out is poisoned before every call)
    hipMemsetAsync(out + (size_t)NTOK * Dq, 0, sizeof(float), stream);

    if (d_ws != nullptr && ws_size >= WS_NEED_BYTES) {
        float* ws = (float*)d_ws;
        rvq_prep<<<dim3(Qq), dim3(512), 0, stream>>>(cb, ws);
        rvq_main<<<dim3(NTOK / 256), dim3(512), 0, stream>>>(
            x, cb, ps, pb, cw, cbias, ws, out);
    } else {
        rvq_mono<<<dim3(NTOK / 256), dim3(512), 0, stream>>>(
            x, cb, ps, pb, cw, cbias, out);
    }
}